// Round 22
// baseline (76.535 us; speedup 1.0000x reference)
//
#include <hip/hip_runtime.h>
#include <hip/hip_bf16.h>
#include <stdint.h>

// S5 layer on MI355X — round 22: r21 base; single contained change (scanCB):
//   carry sum -> 4-way interleaved accumulators (weights stride A^256),
//   recurrence -> 2-way even/odd split (A^2-stride chains, 32 links each).
//   Pure reassociation; all other kernels byte-identical to r21 (74.57 us).

#define BATCH 8
#define SEQ   4096
#define DMODEL 512
#define HALF  64
#define CHUNK 64
#define NCHUNK (SEQ / CHUNK)   // 64
#define NT    10               // 640/64 K-tiles in gemm23 (20 kh-phases)

typedef __attribute__((ext_vector_type(8))) short short8;
typedef __attribute__((ext_vector_type(4))) float f32x4;

__device__ __forceinline__ unsigned short f2bf(float f) {
    unsigned int u = __float_as_uint(f);
    u += 0x7fffu + ((u >> 16) & 1u);
    return (unsigned short)(u >> 16);
}
__device__ __forceinline__ float bf2f(unsigned short s) {
    return __uint_as_float((unsigned)s << 16);
}

// per-thread bilinear A for pole n
__device__ __forceinline__ void poleA(const float* logLr, const float* Li_in,
                                      const float* logDelta, int n,
                                      float& Ar, float& Ai) {
    float Delta = expf(logDelta[0]);
    float llr = fminf(fmaxf(logLr[n], -10.f), 10.f);
    float Lr = -expf(llr);
    float Li = Li_in[n];
    float dr = 1.f - 0.5f * Delta * Lr;
    float di = -0.5f * Delta * Li;
    float dn = dr * dr + di * di;
    float nr = 1.f + 0.5f * Delta * Lr;
    float ni = 0.5f * Delta * Li;
    Ar = (nr * dr + ni * di) / dn;
    Ai = (ni * dr - nr * di) / dn;
}

// complex power A^e (e in [0,63])
__device__ __forceinline__ void cpow(float Ar, float Ai, int e,
                                     float& wr, float& wi) {
    wr = 1.f; wi = 0.f;
    float br = Ar, bi = Ai;
#pragma unroll
    for (int k = 0; k < 6; ++k) {
        if (e & 1) { float t = wr * br - wi * bi; wi = wr * bi + wi * br; wr = t; }
        float t2 = br * br - bi * bi; bi = 2.f * br * bi; br = t2;
        e >>= 1;
    }
}

#define GLOAD_LDS16(g, l)                                                    \
    __builtin_amdgcn_global_load_lds(                                        \
        (const __attribute__((address_space(1))) unsigned int*)(g),          \
        (__attribute__((address_space(3))) unsigned int*)(l), 16, 0, 0)

// ---------------- fused weight build: Mv (blocks 0..127) + W (128..639) ----------------
__global__ void k_build(const float* __restrict__ logLr, const float* __restrict__ Li_in,
                        const float* __restrict__ logDelta,
                        const float* __restrict__ Br, const float* __restrict__ Bi,
                        const float* __restrict__ Cr, const float* __restrict__ Ci,
                        const float* __restrict__ D,
                        unsigned short* __restrict__ Mv, unsigned short* __restrict__ W) {
    int bid = blockIdx.x;
    if (bid < 128) {
        int np = bid, p = threadIdx.x;
        if (p < DMODEL) {
            int n = np & 63;
            float Delta = expf(logDelta[0]);
            float llr = fminf(fmaxf(logLr[n], -10.f), 10.f);
            float Lr = -expf(llr);
            float Li = Li_in[n];
            float dr = 1.f - 0.5f * Delta * Lr;
            float di = -0.5f * Delta * Li;
            float dn = dr * dr + di * di;
            float sr = Delta * dr / dn;
            float si = -Delta * di / dn;
            float br = Br[n * DMODEL + p], bi = Bi[n * DMODEL + p];
            float v = (np < HALF) ? (sr * br - si * bi) : (si * br + sr * bi);
            Mv[np * DMODEL + p] = f2bf(v);
        }
    } else {
        int p = bid - 128, j = threadIdx.x;
        float v;
        if (j < HALF) v = 2.f * Cr[p * HALF + j];
        else if (j < 2 * HALF) v = -2.f * Ci[p * HALF + (j - HALF)];
        else v = D[p * DMODEL + (j - 2 * HALF)];
        W[p * 640 + j] = f2bf(v);
    }
}

// ---------------- scanCB: 4-way-ILP carry + 2-way-ILP recurrence -> Xb ----------------
__global__ void k_scanCB(const unsigned short* __restrict__ Vb,
                         const float* __restrict__ E,
                         const float* __restrict__ logLr, const float* __restrict__ Li_in,
                         const float* __restrict__ logDelta,
                         unsigned short* __restrict__ Xb) {
    int tid = threadIdx.x;
    int n = tid & 63;
    int c = ((blockIdx.x & 31) << 1) + (tid >> 6);
    int b = blockIdx.x >> 5;
    float Ar, Ai;
    poleA(logLr, Li_in, logDelta, n, Ar, Ai);
    float a2r = Ar * Ar - Ai * Ai;
    float a2i = 2.f * Ar * Ai;
    // A^64 = (A^2)^32 by 5 squarings
    float a64r = a2r, a64i = a2i;
#pragma unroll
    for (int s = 0; s < 5; ++s) {
        float t = a64r * a64r - a64i * a64i;
        a64i = 2.f * a64r * a64i;
        a64r = t;
    }
    float a128r = a64r * a64r - a64i * a64i;
    float a128i = 2.f * a64r * a64i;
    float a256r = a128r * a128r - a128i * a128i;
    float a256i = 2.f * a128r * a128i;
    // carry = sum_{jj=1..c} (A^64)^(jj-1) * E_{c-jj}, 4-way interleave
    float x0r = 0.f, x0i = 0.f, x1r = 0.f, x1i = 0.f;
    float x2r = 0.f, x2i = 0.f, x3r = 0.f, x3i = 0.f;
    float w0r = 1.f, w0i = 0.f;
    float w1r = a64r, w1i = a64i;
    float w2r = a128r, w2i = a128i;
    float w3r = a128r * a64r - a128i * a64i;
    float w3i = a128r * a64i + a128i * a64r;   // A^192
    const float* Eb = E + b * NCHUNK * 2 * HALF + n;
    int jj = 1;
    for (; jj + 3 <= c; jj += 4) {
        const float* e0 = Eb + (c - jj) * 2 * HALF;
        const float* e1 = Eb + (c - jj - 1) * 2 * HALF;
        const float* e2 = Eb + (c - jj - 2) * 2 * HALF;
        const float* e3 = Eb + (c - jj - 3) * 2 * HALF;
        float e0r = e0[0], e0v = e0[64];
        float e1r = e1[0], e1v = e1[64];
        float e2r = e2[0], e2v = e2[64];
        float e3r = e3[0], e3v = e3[64];
        x0r += w0r * e0r - w0i * e0v;  x0i += w0r * e0v + w0i * e0r;
        x1r += w1r * e1r - w1i * e1v;  x1i += w1r * e1v + w1i * e1r;
        x2r += w2r * e2r - w2i * e2v;  x2i += w2r * e2v + w2i * e2r;
        x3r += w3r * e3r - w3i * e3v;  x3i += w3r * e3v + w3i * e3r;
        float t0r = w0r * a256r - w0i * a256i, t0i = w0r * a256i + w0i * a256r;
        float t1r = w1r * a256r - w1i * a256i, t1i = w1r * a256i + w1i * a256r;
        float t2r = w2r * a256r - w2i * a256i, t2i = w2r * a256i + w2i * a256r;
        float t3r = w3r * a256r - w3i * a256i, t3i = w3r * a256i + w3i * a256r;
        w0r = t0r; w0i = t0i; w1r = t1r; w1i = t1i;
        w2r = t2r; w2i = t2i; w3r = t3r; w3i = t3i;
    }
    // remainder (<=3): weights w0, w1, w2 are exactly (A^64)^(jj-1), ^(jj), ^(jj+1)
    if (jj <= c) {
        const float* e0 = Eb + (c - jj) * 2 * HALF;
        float er = e0[0], ev = e0[64];
        x0r += w0r * er - w0i * ev;  x0i += w0r * ev + w0i * er;
        ++jj;
    }
    if (jj <= c) {
        const float* e0 = Eb + (c - jj) * 2 * HALF;
        float er = e0[0], ev = e0[64];
        x1r += w1r * er - w1i * ev;  x1i += w1r * ev + w1i * er;
        ++jj;
    }
    if (jj <= c) {
        const float* e0 = Eb + (c - jj) * 2 * HALF;
        float er = e0[0], ev = e0[64];
        x2r += w2r * er - w2i * ev;  x2i += w2r * ev + w2i * er;
    }
    float cr = (x0r + x1r) + (x2r + x3r);
    float ci = (x0i + x1i) + (x2i + x3i);

    // 2-way even/odd recurrence: x[2k] and x[2k+1] chains with A^2 stride
    size_t base = ((size_t)b * SEQ + (size_t)c * CHUNK) * 128 + n;
    // k = 0: x[0] = A*c + v0 ; x[1] = A^2*c + (A*v0 + v1)
    float v0r = bf2f(Vb[base]),       v0i = bf2f(Vb[base + 64]);
    float v1r = bf2f(Vb[base + 128]), v1i = bf2f(Vb[base + 192]);
    float xer = Ar * cr - Ai * ci + v0r;
    float xei = Ar * ci + Ai * cr + v0i;
    float tor = Ar * v0r - Ai * v0i + v1r;
    float toi = Ar * v0i + Ai * v0r + v1i;
    float xor_ = a2r * cr - a2i * ci + tor;
    float xoi  = a2r * ci + a2i * cr + toi;
    Xb[base]       = f2bf(xer);  Xb[base + 64]  = f2bf(xei);
    Xb[base + 128] = f2bf(xor_); Xb[base + 192] = f2bf(xoi);
    float p1r = v1r, p1i = v1i;
    base += 256;
    for (int k = 1; k < 32; ++k) {
        float var = bf2f(Vb[base]),       vai = bf2f(Vb[base + 64]);   // v[2k]
        float vbr = bf2f(Vb[base + 128]), vbi = bf2f(Vb[base + 192]);  // v[2k+1]
        float ter = Ar * p1r - Ai * p1i + var;     // A*v[2k-1] + v[2k]
        float tei = Ar * p1i + Ai * p1r + vai;
        float t2r = Ar * var - Ai * vai + vbr;     // A*v[2k] + v[2k+1]
        float t2i = Ar * vai + Ai * var + vbi;
        float nxer = a2r * xer - a2i * xei + ter;
        float nxei = a2r * xei + a2i * xer + tei;
        xer = nxer; xei = nxei;
        float nxor = a2r * xor_ - a2i * xoi + t2r;
        float nxoi = a2r * xoi + a2i * xor_ + t2i;
        xor_ = nxor; xoi = nxoi;
        Xb[base]       = f2bf(xer);  Xb[base + 64]  = f2bf(xei);
        Xb[base + 128] = f2bf(xor_); Xb[base + 192] = f2bf(xoi);
        p1r = vbr; p1i = vbi;
        base += 256;
    }
}

// ---------------- GEMM1: Vb = bf16(U @ Mv^T), Ub = bf16(U), E = chunk-end states ----------------
__global__ __launch_bounds__(512) void gemm1(const float* __restrict__ U,
                                             const unsigned short* __restrict__ Mv,
                                             unsigned short* __restrict__ Vb,
                                             unsigned short* __restrict__ Ub,
                                             const float* __restrict__ logLr,
                                             const float* __restrict__ Li_in,
                                             const float* __restrict__ logDelta,
                                             float* __restrict__ E) {
    __shared__ __align__(16) unsigned short As[64 * 32];
    __shared__ __align__(16) unsigned short Bs[128 * 32];
    __shared__ float Ered[8][2][16][2];   // [wave][nf][l15][re/im-target] = 2 KB
    const int tid = threadIdx.x;
    const int lane = tid & 63;
    const int w = tid >> 6;            // 0..7
    const int wm = w >> 2, wn = w & 3; // 2 x 4
    const int l15 = lane & 15, l4 = lane >> 4;
    const int row0 = blockIdx.x * 64;
    const int srow = tid >> 3;         // 0..63
    const int sh = (tid & 7) * 4;      // 0..28

    f32x4 acc[2][2];
#pragma unroll
    for (int m = 0; m < 2; ++m)
#pragma unroll
        for (int n = 0; n < 2; ++n) acc[m][n] = (f32x4)(0.f);

    for (int k0 = 0; k0 < DMODEL; k0 += 32) {
        const float4 av = *(const float4*)(U + (size_t)(row0 + srow) * DMODEL + k0 + sh);

        __syncthreads();   // prior tile's LDS reads complete

        GLOAD_LDS16(Mv + (size_t)(tid >> 2) * DMODEL + k0 + (tid & 3) * 8,
                    &Bs[(w * 64) * 8]);

        uint2 wa;
        wa.x = (unsigned)f2bf(av.x) | ((unsigned)f2bf(av.y) << 16);
        wa.y = (unsigned)f2bf(av.z) | ((unsigned)f2bf(av.w) << 16);
        *(uint2*)&As[srow * 32 + sh] = wa;
        *(uint2*)&Ub[(size_t)(row0 + srow) * DMODEL + k0 + sh] = wa;

        __syncthreads();   // vmcnt+lgkm drain: tiles staged

        short8 af[2], bf[2];
#pragma unroll
        for (int m = 0; m < 2; ++m)
            af[m] = *(const short8*)&As[(wm * 32 + m * 16 + l15) * 32 + l4 * 8];
#pragma unroll
        for (int n = 0; n < 2; ++n)
            bf[n] = *(const short8*)&Bs[(wn * 32 + n * 16 + l15) * 32 + l4 * 8];
#pragma unroll
        for (int m = 0; m < 2; ++m)
#pragma unroll
            for (int n = 0; n < 2; ++n)
                acc[m][n] = __builtin_amdgcn_mfma_f32_16x16x32_bf16(af[m], bf[n], acc[m][n], 0, 0, 0);
    }

    // ---- Vb write (raw v) ----
#pragma unroll
    for (int m = 0; m < 2; ++m) {
        int rbase = row0 + wm * 32 + m * 16 + l4 * 4;
#pragma unroll
        for (int n = 0; n < 2; ++n) {
            int col = wn * 32 + n * 16 + l15;
#pragma unroll
            for (int r = 0; r < 4; ++r)
                Vb[(size_t)(rbase + r) * 128 + col] = f2bf(acc[m][n][r]);
        }
    }

    // ---- E epilogue: weighted reduction over t ----
    {
        const int base = wm * 32 + l4 * 4;
        const int isIm = (wn >= 2);
#pragma unroll
        for (int nf = 0; nf < 2; ++nf) {
            int pole = ((wn & 1) * 32) + nf * 16 + l15;
            float Ar, Ai;
            poleA(logLr, Li_in, logDelta, pole, Ar, Ai);
            float a2r = Ar * Ar - Ai * Ai, a2i = 2.f * Ar * Ai;
            float a4r = a2r * a2r - a2i * a2i, a4i = 2.f * a2r * a2i;
            float a8r = a4r * a4r - a4i * a4i, a8i = 2.f * a4r * a4i;
            float a12r = a8r * a4r - a8i * a4i, a12i = a8r * a4i + a8i * a4r;
            float wr, wi;
            cpow(Ar, Ai, 44 - base, wr, wi);
            float s2re = 0.f, s2im = 0.f;
#pragma unroll
            for (int m = 1; m >= 0; --m) {
#pragma unroll
                for (int r = 3; r >= 0; --r) {
                    float v = acc[m][nf][r];
                    if (isIm) { s2re -= wi * v; s2im += wr * v; }
                    else      { s2re += wr * v; s2im += wi * v; }
                    float nwr = wr * Ar - wi * Ai;
                    float nwi = wr * Ai + wi * Ar;
                    wr = nwr; wi = nwi;
                }
                if (m == 1) {
                    float nwr = wr * a12r - wi * a12i;
                    float nwi = wr * a12i + wi * a12r;
                    wr = nwr; wi = nwi;
                }
            }
            s2re += __shfl_xor(s2re, 16, 64);
            s2re += __shfl_xor(s2re, 32, 64);
            s2im += __shfl_xor(s2im, 16, 64);
            s2im += __shfl_xor(s2im, 32, 64);
            if (l4 == 0) {
                Ered[w][nf][l15][0] = s2re;
                Ered[w][nf][l15][1] = s2im;
            }
        }
    }
    __syncthreads();
    if (tid < 128) {
        int p = tid & 63;           // pole
        int comp = tid >> 6;        // 0 = re, 1 = im
        int wn1 = p >> 5;
        int nf = (p >> 4) & 1;
        int l = p & 15;
        float s = Ered[0 * 4 + wn1][nf][l][comp] + Ered[0 * 4 + wn1 + 2][nf][l][comp]
                + Ered[1 * 4 + wn1][nf][l][comp] + Ered[1 * 4 + wn1 + 2][nf][l][comp];
        int b = row0 >> 12;             // batch
        int c = (row0 >> 6) & 63;       // chunk
        E[((b * NCHUNK + c) * 2) * HALF + comp * 64 + p] = s;
    }
}

// ---------------- GEMM23: out = [Xb | Ub] @ W^T, swapped-operand ----------------

#define STAGE_K(t, kh, j) do {                                                 \
    int c_ = (kh) * 1024 + (j) * 512 + tid;                                    \
    int ct_ = c_ ^ (((c_ >> 5) & 1) << 1);                                     \
    int r_ = (ct_ >> 2) & 255;                                                 \
    int kcol_ = (t) * 64 + (kh) * 32 + (ct_ & 3) * 8;                          \
    const unsigned short* asrc_ = (kcol_ < 128)                                \
        ? Xb + (size_t)(row0 + r_) * 128 + kcol_                               \
        : Ub + (size_t)(row0 + r_) * 512 + (kcol_ - 128);                      \
    GLOAD_LDS16(asrc_, &As[((t) & 1) * 16384 + ((kh) * 1024 + (j) * 512 + w * 64) * 8]); \
    GLOAD_LDS16(W + (size_t)(col0 + r_) * 640 + kcol_,                         \
                &Bs[((t) & 1) * 16384 + ((kh) * 1024 + (j) * 512 + w * 64) * 8]); \
} while (0)

#define LDAB(t, kh) do {                                                       \
    _Pragma("unroll") for (int i_ = 0; i_ < 8; ++i_) {                         \
        int r_ = wm * 128 + i_ * 16 + l15;                                     \
        int c_ = (l4 * 8) ^ (((r_ >> 3) & 1) << 4);                            \
        af[i_] = *(const short8*)&As[((t) & 1) * 16384 + (kh) * 8192 + r_ * 32 + c_]; \
    }                                                                          \
    _Pragma("unroll") for (int j_ = 0; j_ < 4; ++j_) {                         \
        int r_ = wn * 64 + j_ * 16 + l15;                                      \
        int c_ = (l4 * 8) ^ (((r_ >> 3) & 1) << 4);                            \
        bf[j_] = *(const short8*)&Bs[((t) & 1) * 16384 + (kh) * 8192 + r_ * 32 + c_]; \
    } } while (0)

// swapped operands: D^T — acc reg index = out-column offset
#define MFMA32() do {                                                          \
    __builtin_amdgcn_s_setprio(1);                                             \
    _Pragma("unroll") for (int i_ = 0; i_ < 8; ++i_)                           \
    _Pragma("unroll") for (int j_ = 0; j_ < 4; ++j_)                           \
        acc[i_][j_] = __builtin_amdgcn_mfma_f32_16x16x32_bf16(                 \
            bf[j_], af[i_], acc[i_][j_], 0, 0, 0);                             \
    __builtin_amdgcn_s_setprio(0);                                             \
} while (0)

#define PHASE_SYNC(N) do {                                                     \
    asm volatile("s_waitcnt vmcnt(" #N ")" ::: "memory");                      \
    __builtin_amdgcn_s_barrier();                                              \
    __builtin_amdgcn_sched_barrier(0);                                         \
} while (0)

__global__ __launch_bounds__(512) void gemm23_8p(const unsigned short* __restrict__ Xb,
                                                 const unsigned short* __restrict__ Ub,
                                                 const unsigned short* __restrict__ W,
                                                 float* __restrict__ C) {
    __shared__ __align__(16) unsigned short As[2 * 16384];  // 64 KiB = 4 kh-slots
    __shared__ __align__(16) unsigned short Bs[2 * 16384];  // 64 KiB
    const int tid = threadIdx.x;
    const int lane = tid & 63;
    const int w = tid >> 6;             // 0..7
    const int wm = w >> 2, wn = w & 3;  // 2 x 4
    const int l15 = lane & 15, l4 = lane >> 4;

    // T1: bijective XCD swizzle over 256 blocks
    int lin = blockIdx.y * gridDim.x + blockIdx.x;  // 0..255
    int sw = (lin & 7) * 32 + (lin >> 3);
    const int row0 = (sw & 127) * 256;
    const int col0 = (sw >> 7) * 256;

    f32x4 acc[8][4];
#pragma unroll
    for (int m = 0; m < 8; ++m)
#pragma unroll
        for (int n = 0; n < 4; ++n) acc[m][n] = (f32x4)(0.f);

    // prologue: stage kh-phases 0,1,2 (12 loads/thread in flight)
    STAGE_K(0, 0, 0); STAGE_K(0, 0, 1);
    STAGE_K(0, 1, 0); STAGE_K(0, 1, 1);
    STAGE_K(1, 0, 0); STAGE_K(1, 0, 1);

    short8 af[8], bf[4];
    for (int t = 0; t < NT - 1; ++t) {   // t = 0..8
        PHASE_SYNC(8);
        LDAB(t, 0);
        STAGE_K(t + 1, 1, 0); STAGE_K(t + 1, 1, 1);
        MFMA32();
        PHASE_SYNC(8);
        LDAB(t, 1);
        if (t < NT - 2) { STAGE_K(t + 2, 0, 0); STAGE_K(t + 2, 0, 1); }
        MFMA32();
    }
    PHASE_SYNC(4);
    LDAB(NT - 1, 0);
    MFMA32();
    PHASE_SYNC(0);
    LDAB(NT - 1, 1);
    MFMA32();

    // epilogue: D^T layout -> reg r = out-col offset; dwordx4 stores
#pragma unroll
    for (int i = 0; i < 8; ++i) {
        int row = row0 + wm * 128 + i * 16 + l15;
#pragma unroll
        for (int j = 0; j < 4; ++j) {
            int col = col0 + wn * 64 + j * 16 + l4 * 4;
            *(float4*)&C[(size_t)row * DMODEL + col] =
                make_float4(acc[i][j][0], acc[i][j][1], acc[i][j][2], acc[i][j][3]);
        }
    }
}

// ---------------- launch ----------------

extern "C" void kernel_launch(void* const* d_in, const int* in_sizes, int n_in,
                              void* d_out, int out_size, void* d_ws, size_t ws_size,
                              hipStream_t stream) {
    const float* u      = (const float*)d_in[0];
    const float* logLr  = (const float*)d_in[1];
    const float* Li     = (const float*)d_in[2];
    const float* Br     = (const float*)d_in[3];
    const float* Bi     = (const float*)d_in[4];
    const float* Cr     = (const float*)d_in[5];
    const float* Ci     = (const float*)d_in[6];
    const float* D      = (const float*)d_in[7];
    const float* logDel = (const float*)d_in[8];
    float* out = (float*)d_out;

    const size_t M = (size_t)BATCH * SEQ;  // 32768
    unsigned short* Vb = (unsigned short*)d_ws;       // M*128
    unsigned short* Ub = Vb + M * 128;                // M*512
    unsigned short* Xb = Ub + M * 512;                // M*128
    unsigned short* Mv = Xb + M * 128;                // 128*512
    unsigned short* W  = Mv + 128 * 512;              // 512*640
    float* E     = (float*)(W + 512 * 640);           // 65536

    // fused weight build (Mv + W)
    hipLaunchKernelGGL(k_build, dim3(640), dim3(640), 0, stream,
                       logLr, Li, logDel, Br, Bi, Cr, Ci, D, Mv, W);

    // GEMM1: Vb = bf16(U @ Mv^T), Ub = bf16(U), E = chunk-end states (fused)
    hipLaunchKernelGGL(gemm1, dim3(M / 64), dim3(512), 0, stream,
                       u, Mv, Vb, Ub, logLr, Li, logDel, E);

    // scan: 4-way-ILP carry + 2-way-ILP recurrence -> Xb
    hipLaunchKernelGGL(k_scanCB, dim3(256), dim3(128), 0, stream,
                       Vb, E, logLr, Li, logDel, Xb);

    // GEMM23: out = [Xb | Ub] @ W^T
    hipLaunchKernelGGL(gemm23_8p, dim3(M / 256, DMODEL / 256), dim3(512), 0, stream,
                       Xb, Ub, W, out);
}

// Round 23
// 74.061 us; speedup vs baseline: 1.0334x; 1.0334x over previous
//
#include <hip/hip_runtime.h>
#include <hip/hip_bf16.h>
#include <stdint.h>

// S5 layer on MI355X — round 23: r21 base (74.57 us); ISOLATED single change:
//   scanCB carry sum 2-way -> 4-way interleave (weights stride A^256).
//   Recurrence stays r21's simple serial 64-step chain (r22's 2-way recurrence
//   split regressed — doubled off-chain VALU work). Pure reassociation.
//   All other kernels byte-identical to r21.

#define BATCH 8
#define SEQ   4096
#define DMODEL 512
#define HALF  64
#define CHUNK 64
#define NCHUNK (SEQ / CHUNK)   // 64
#define NT    10               // 640/64 K-tiles in gemm23 (20 kh-phases)

typedef __attribute__((ext_vector_type(8))) short short8;
typedef __attribute__((ext_vector_type(4))) float f32x4;

__device__ __forceinline__ unsigned short f2bf(float f) {
    unsigned int u = __float_as_uint(f);
    u += 0x7fffu + ((u >> 16) & 1u);
    return (unsigned short)(u >> 16);
}
__device__ __forceinline__ float bf2f(unsigned short s) {
    return __uint_as_float((unsigned)s << 16);
}

// per-thread bilinear A for pole n
__device__ __forceinline__ void poleA(const float* logLr, const float* Li_in,
                                      const float* logDelta, int n,
                                      float& Ar, float& Ai) {
    float Delta = expf(logDelta[0]);
    float llr = fminf(fmaxf(logLr[n], -10.f), 10.f);
    float Lr = -expf(llr);
    float Li = Li_in[n];
    float dr = 1.f - 0.5f * Delta * Lr;
    float di = -0.5f * Delta * Li;
    float dn = dr * dr + di * di;
    float nr = 1.f + 0.5f * Delta * Lr;
    float ni = 0.5f * Delta * Li;
    Ar = (nr * dr + ni * di) / dn;
    Ai = (ni * dr - nr * di) / dn;
}

// complex power A^e (e in [0,63])
__device__ __forceinline__ void cpow(float Ar, float Ai, int e,
                                     float& wr, float& wi) {
    wr = 1.f; wi = 0.f;
    float br = Ar, bi = Ai;
#pragma unroll
    for (int k = 0; k < 6; ++k) {
        if (e & 1) { float t = wr * br - wi * bi; wi = wr * bi + wi * br; wr = t; }
        float t2 = br * br - bi * bi; bi = 2.f * br * bi; br = t2;
        e >>= 1;
    }
}

#define GLOAD_LDS16(g, l)                                                    \
    __builtin_amdgcn_global_load_lds(                                        \
        (const __attribute__((address_space(1))) unsigned int*)(g),          \
        (__attribute__((address_space(3))) unsigned int*)(l), 16, 0, 0)

// ---------------- fused weight build: Mv (blocks 0..127) + W (128..639) ----------------
__global__ void k_build(const float* __restrict__ logLr, const float* __restrict__ Li_in,
                        const float* __restrict__ logDelta,
                        const float* __restrict__ Br, const float* __restrict__ Bi,
                        const float* __restrict__ Cr, const float* __restrict__ Ci,
                        const float* __restrict__ D,
                        unsigned short* __restrict__ Mv, unsigned short* __restrict__ W) {
    int bid = blockIdx.x;
    if (bid < 128) {
        int np = bid, p = threadIdx.x;
        if (p < DMODEL) {
            int n = np & 63;
            float Delta = expf(logDelta[0]);
            float llr = fminf(fmaxf(logLr[n], -10.f), 10.f);
            float Lr = -expf(llr);
            float Li = Li_in[n];
            float dr = 1.f - 0.5f * Delta * Lr;
            float di = -0.5f * Delta * Li;
            float dn = dr * dr + di * di;
            float sr = Delta * dr / dn;
            float si = -Delta * di / dn;
            float br = Br[n * DMODEL + p], bi = Bi[n * DMODEL + p];
            float v = (np < HALF) ? (sr * br - si * bi) : (si * br + sr * bi);
            Mv[np * DMODEL + p] = f2bf(v);
        }
    } else {
        int p = bid - 128, j = threadIdx.x;
        float v;
        if (j < HALF) v = 2.f * Cr[p * HALF + j];
        else if (j < 2 * HALF) v = -2.f * Ci[p * HALF + (j - HALF)];
        else v = D[p * DMODEL + (j - 2 * HALF)];
        W[p * 640 + j] = f2bf(v);
    }
}

// ---------------- scanCB: 4-way-ILP carry sum + serial recurrence -> Xb ----------------
__global__ void k_scanCB(const unsigned short* __restrict__ Vb,
                         const float* __restrict__ E,
                         const float* __restrict__ logLr, const float* __restrict__ Li_in,
                         const float* __restrict__ logDelta,
                         unsigned short* __restrict__ Xb) {
    int tid = threadIdx.x;
    int n = tid & 63;
    int c = ((blockIdx.x & 31) << 1) + (tid >> 6);
    int b = blockIdx.x >> 5;
    float Ar, Ai;
    poleA(logLr, Li_in, logDelta, n, Ar, Ai);
    float a64r = Ar, a64i = Ai;
#pragma unroll
    for (int s = 0; s < 6; ++s) {
        float t = a64r * a64r - a64i * a64i;
        a64i = 2.f * a64r * a64i;
        a64r = t;
    }
    float a128r = a64r * a64r - a64i * a64i;
    float a128i = 2.f * a64r * a64i;
    float a256r = a128r * a128r - a128i * a128i;
    float a256i = 2.f * a128r * a128i;
    // carry = sum_{jj=1..c} (A^64)^(jj-1) * E_{c-jj}, 4-way interleave
    float x0r = 0.f, x0i = 0.f, x1r = 0.f, x1i = 0.f;
    float x2r = 0.f, x2i = 0.f, x3r = 0.f, x3i = 0.f;
    float w0r = 1.f, w0i = 0.f;
    float w1r = a64r, w1i = a64i;
    float w2r = a128r, w2i = a128i;
    float w3r = a128r * a64r - a128i * a64i;
    float w3i = a128r * a64i + a128i * a64r;   // A^192
    const float* Eb = E + b * NCHUNK * 2 * HALF + n;
    int jj = 1;
    for (; jj + 3 <= c; jj += 4) {
        const float* e0 = Eb + (c - jj) * 2 * HALF;
        const float* e1 = Eb + (c - jj - 1) * 2 * HALF;
        const float* e2 = Eb + (c - jj - 2) * 2 * HALF;
        const float* e3 = Eb + (c - jj - 3) * 2 * HALF;
        float e0r = e0[0], e0v = e0[64];
        float e1r = e1[0], e1v = e1[64];
        float e2r = e2[0], e2v = e2[64];
        float e3r = e3[0], e3v = e3[64];
        x0r += w0r * e0r - w0i * e0v;  x0i += w0r * e0v + w0i * e0r;
        x1r += w1r * e1r - w1i * e1v;  x1i += w1r * e1v + w1i * e1r;
        x2r += w2r * e2r - w2i * e2v;  x2i += w2r * e2v + w2i * e2r;
        x3r += w3r * e3r - w3i * e3v;  x3i += w3r * e3v + w3i * e3r;
        float t0r = w0r * a256r - w0i * a256i, t0i = w0r * a256i + w0i * a256r;
        float t1r = w1r * a256r - w1i * a256i, t1i = w1r * a256i + w1i * a256r;
        float t2r = w2r * a256r - w2i * a256i, t2i = w2r * a256i + w2i * a256r;
        float t3r = w3r * a256r - w3i * a256i, t3i = w3r * a256i + w3i * a256r;
        w0r = t0r; w0i = t0i; w1r = t1r; w1i = t1i;
        w2r = t2r; w2i = t2i; w3r = t3r; w3i = t3i;
    }
    // remainder (<=3): w0/w1/w2 are exactly (A^64)^(jj-1), ^(jj), ^(jj+1)
    if (jj <= c) {
        const float* e0 = Eb + (c - jj) * 2 * HALF;
        float er = e0[0], ev = e0[64];
        x0r += w0r * er - w0i * ev;  x0i += w0r * ev + w0i * er;
        ++jj;
    }
    if (jj <= c) {
        const float* e0 = Eb + (c - jj) * 2 * HALF;
        float er = e0[0], ev = e0[64];
        x1r += w1r * er - w1i * ev;  x1i += w1r * ev + w1i * er;
        ++jj;
    }
    if (jj <= c) {
        const float* e0 = Eb + (c - jj) * 2 * HALF;
        float er = e0[0], ev = e0[64];
        x2r += w2r * er - w2i * ev;  x2i += w2r * ev + w2i * er;
    }
    float xr = (x0r + x1r) + (x2r + x3r);
    float xi = (x0i + x1i) + (x2i + x3i);
    // seeded recurrence over the chunk (r21's simple serial chain)
    size_t base = ((size_t)b * SEQ + (size_t)c * CHUNK) * 128 + n;
    for (int tl = 0; tl < CHUNK; ++tl) {
        float vr = bf2f(Vb[base]), vi = bf2f(Vb[base + 64]);
        float nxr = Ar * xr - Ai * xi + vr;
        float nxi = Ar * xi + Ai * xr + vi;
        xr = nxr; xi = nxi;
        Xb[base] = f2bf(xr); Xb[base + 64] = f2bf(xi);
        base += 128;
    }
}

// ---------------- GEMM1: Vb = bf16(U @ Mv^T), Ub = bf16(U), E = chunk-end states ----------------
__global__ __launch_bounds__(512) void gemm1(const float* __restrict__ U,
                                             const unsigned short* __restrict__ Mv,
                                             unsigned short* __restrict__ Vb,
                                             unsigned short* __restrict__ Ub,
                                             const float* __restrict__ logLr,
                                             const float* __restrict__ Li_in,
                                             const float* __restrict__ logDelta,
                                             float* __restrict__ E) {
    __shared__ __align__(16) unsigned short As[64 * 32];
    __shared__ __align__(16) unsigned short Bs[128 * 32];
    __shared__ float Ered[8][2][16][2];   // [wave][nf][l15][re/im-target] = 2 KB
    const int tid = threadIdx.x;
    const int lane = tid & 63;
    const int w = tid >> 6;            // 0..7
    const int wm = w >> 2, wn = w & 3; // 2 x 4
    const int l15 = lane & 15, l4 = lane >> 4;
    const int row0 = blockIdx.x * 64;
    const int srow = tid >> 3;         // 0..63
    const int sh = (tid & 7) * 4;      // 0..28

    f32x4 acc[2][2];
#pragma unroll
    for (int m = 0; m < 2; ++m)
#pragma unroll
        for (int n = 0; n < 2; ++n) acc[m][n] = (f32x4)(0.f);

    for (int k0 = 0; k0 < DMODEL; k0 += 32) {
        const float4 av = *(const float4*)(U + (size_t)(row0 + srow) * DMODEL + k0 + sh);

        __syncthreads();   // prior tile's LDS reads complete

        GLOAD_LDS16(Mv + (size_t)(tid >> 2) * DMODEL + k0 + (tid & 3) * 8,
                    &Bs[(w * 64) * 8]);

        uint2 wa;
        wa.x = (unsigned)f2bf(av.x) | ((unsigned)f2bf(av.y) << 16);
        wa.y = (unsigned)f2bf(av.z) | ((unsigned)f2bf(av.w) << 16);
        *(uint2*)&As[srow * 32 + sh] = wa;
        *(uint2*)&Ub[(size_t)(row0 + srow) * DMODEL + k0 + sh] = wa;

        __syncthreads();   // vmcnt+lgkm drain: tiles staged

        short8 af[2], bf[2];
#pragma unroll
        for (int m = 0; m < 2; ++m)
            af[m] = *(const short8*)&As[(wm * 32 + m * 16 + l15) * 32 + l4 * 8];
#pragma unroll
        for (int n = 0; n < 2; ++n)
            bf[n] = *(const short8*)&Bs[(wn * 32 + n * 16 + l15) * 32 + l4 * 8];
#pragma unroll
        for (int m = 0; m < 2; ++m)
#pragma unroll
            for (int n = 0; n < 2; ++n)
                acc[m][n] = __builtin_amdgcn_mfma_f32_16x16x32_bf16(af[m], bf[n], acc[m][n], 0, 0, 0);
    }

    // ---- Vb write (raw v) ----
#pragma unroll
    for (int m = 0; m < 2; ++m) {
        int rbase = row0 + wm * 32 + m * 16 + l4 * 4;
#pragma unroll
        for (int n = 0; n < 2; ++n) {
            int col = wn * 32 + n * 16 + l15;
#pragma unroll
            for (int r = 0; r < 4; ++r)
                Vb[(size_t)(rbase + r) * 128 + col] = f2bf(acc[m][n][r]);
        }
    }

    // ---- E epilogue: weighted reduction over t ----
    {
        const int base = wm * 32 + l4 * 4;
        const int isIm = (wn >= 2);
#pragma unroll
        for (int nf = 0; nf < 2; ++nf) {
            int pole = ((wn & 1) * 32) + nf * 16 + l15;
            float Ar, Ai;
            poleA(logLr, Li_in, logDelta, pole, Ar, Ai);
            float a2r = Ar * Ar - Ai * Ai, a2i = 2.f * Ar * Ai;
            float a4r = a2r * a2r - a2i * a2i, a4i = 2.f * a2r * a2i;
            float a8r = a4r * a4r - a4i * a4i, a8i = 2.f * a4r * a4i;
            float a12r = a8r * a4r - a8i * a4i, a12i = a8r * a4i + a8i * a4r;
            float wr, wi;
            cpow(Ar, Ai, 44 - base, wr, wi);
            float s2re = 0.f, s2im = 0.f;
#pragma unroll
            for (int m = 1; m >= 0; --m) {
#pragma unroll
                for (int r = 3; r >= 0; --r) {
                    float v = acc[m][nf][r];
                    if (isIm) { s2re -= wi * v; s2im += wr * v; }
                    else      { s2re += wr * v; s2im += wi * v; }
                    float nwr = wr * Ar - wi * Ai;
                    float nwi = wr * Ai + wi * Ar;
                    wr = nwr; wi = nwi;
                }
                if (m == 1) {
                    float nwr = wr * a12r - wi * a12i;
                    float nwi = wr * a12i + wi * a12r;
                    wr = nwr; wi = nwi;
                }
            }
            s2re += __shfl_xor(s2re, 16, 64);
            s2re += __shfl_xor(s2re, 32, 64);
            s2im += __shfl_xor(s2im, 16, 64);
            s2im += __shfl_xor(s2im, 32, 64);
            if (l4 == 0) {
                Ered[w][nf][l15][0] = s2re;
                Ered[w][nf][l15][1] = s2im;
            }
        }
    }
    __syncthreads();
    if (tid < 128) {
        int p = tid & 63;           // pole
        int comp = tid >> 6;        // 0 = re, 1 = im
        int wn1 = p >> 5;
        int nf = (p >> 4) & 1;
        int l = p & 15;
        float s = Ered[0 * 4 + wn1][nf][l][comp] + Ered[0 * 4 + wn1 + 2][nf][l][comp]
                + Ered[1 * 4 + wn1][nf][l][comp] + Ered[1 * 4 + wn1 + 2][nf][l][comp];
        int b = row0 >> 12;             // batch
        int c = (row0 >> 6) & 63;       // chunk
        E[((b * NCHUNK + c) * 2) * HALF + comp * 64 + p] = s;
    }
}

// ---------------- GEMM23: out = [Xb | Ub] @ W^T, swapped-operand ----------------

#define STAGE_K(t, kh, j) do {                                                 \
    int c_ = (kh) * 1024 + (j) * 512 + tid;                                    \
    int ct_ = c_ ^ (((c_ >> 5) & 1) << 1);                                     \
    int r_ = (ct_ >> 2) & 255;                                                 \
    int kcol_ = (t) * 64 + (kh) * 32 + (ct_ & 3) * 8;                          \
    const unsigned short* asrc_ = (kcol_ < 128)                                \
        ? Xb + (size_t)(row0 + r_) * 128 + kcol_                               \
        : Ub + (size_t)(row0 + r_) * 512 + (kcol_ - 128);                      \
    GLOAD_LDS16(asrc_, &As[((t) & 1) * 16384 + ((kh) * 1024 + (j) * 512 + w * 64) * 8]); \
    GLOAD_LDS16(W + (size_t)(col0 + r_) * 640 + kcol_,                         \
                &Bs[((t) & 1) * 16384 + ((kh) * 1024 + (j) * 512 + w * 64) * 8]); \
} while (0)

#define LDAB(t, kh) do {                                                       \
    _Pragma("unroll") for (int i_ = 0; i_ < 8; ++i_) {                         \
        int r_ = wm * 128 + i_ * 16 + l15;                                     \
        int c_ = (l4 * 8) ^ (((r_ >> 3) & 1) << 4);                            \
        af[i_] = *(const short8*)&As[((t) & 1) * 16384 + (kh) * 8192 + r_ * 32 + c_]; \
    }                                                                          \
    _Pragma("unroll") for (int j_ = 0; j_ < 4; ++j_) {                         \
        int r_ = wn * 64 + j_ * 16 + l15;                                      \
        int c_ = (l4 * 8) ^ (((r_ >> 3) & 1) << 4);                            \
        bf[j_] = *(const short8*)&Bs[((t) & 1) * 16384 + (kh) * 8192 + r_ * 32 + c_]; \
    } } while (0)

// swapped operands: D^T — acc reg index = out-column offset
#define MFMA32() do {                                                          \
    __builtin_amdgcn_s_setprio(1);                                             \
    _Pragma("unroll") for (int i_ = 0; i_ < 8; ++i_)                           \
    _Pragma("unroll") for (int j_ = 0; j_ < 4; ++j_)                           \
        acc[i_][j_] = __builtin_amdgcn_mfma_f32_16x16x32_bf16(                 \
            bf[j_], af[i_], acc[i_][j_], 0, 0, 0);                             \
    __builtin_amdgcn_s_setprio(0);                                             \
} while (0)

#define PHASE_SYNC(N) do {                                                     \
    asm volatile("s_waitcnt vmcnt(" #N ")" ::: "memory");                      \
    __builtin_amdgcn_s_barrier();                                              \
    __builtin_amdgcn_sched_barrier(0);                                         \
} while (0)

__global__ __launch_bounds__(512) void gemm23_8p(const unsigned short* __restrict__ Xb,
                                                 const unsigned short* __restrict__ Ub,
                                                 const unsigned short* __restrict__ W,
                                                 float* __restrict__ C) {
    __shared__ __align__(16) unsigned short As[2 * 16384];  // 64 KiB = 4 kh-slots
    __shared__ __align__(16) unsigned short Bs[2 * 16384];  // 64 KiB
    const int tid = threadIdx.x;
    const int lane = tid & 63;
    const int w = tid >> 6;             // 0..7
    const int wm = w >> 2, wn = w & 3;  // 2 x 4
    const int l15 = lane & 15, l4 = lane >> 4;

    // T1: bijective XCD swizzle over 256 blocks
    int lin = blockIdx.y * gridDim.x + blockIdx.x;  // 0..255
    int sw = (lin & 7) * 32 + (lin >> 3);
    const int row0 = (sw & 127) * 256;
    const int col0 = (sw >> 7) * 256;

    f32x4 acc[8][4];
#pragma unroll
    for (int m = 0; m < 8; ++m)
#pragma unroll
        for (int n = 0; n < 4; ++n) acc[m][n] = (f32x4)(0.f);

    // prologue: stage kh-phases 0,1,2 (12 loads/thread in flight)
    STAGE_K(0, 0, 0); STAGE_K(0, 0, 1);
    STAGE_K(0, 1, 0); STAGE_K(0, 1, 1);
    STAGE_K(1, 0, 0); STAGE_K(1, 0, 1);

    short8 af[8], bf[4];
    for (int t = 0; t < NT - 1; ++t) {   // t = 0..8
        PHASE_SYNC(8);
        LDAB(t, 0);
        STAGE_K(t + 1, 1, 0); STAGE_K(t + 1, 1, 1);
        MFMA32();
        PHASE_SYNC(8);
        LDAB(t, 1);
        if (t < NT - 2) { STAGE_K(t + 2, 0, 0); STAGE_K(t + 2, 0, 1); }
        MFMA32();
    }
    PHASE_SYNC(4);
    LDAB(NT - 1, 0);
    MFMA32();
    PHASE_SYNC(0);
    LDAB(NT - 1, 1);
    MFMA32();

    // epilogue: D^T layout -> reg r = out-col offset; dwordx4 stores
#pragma unroll
    for (int i = 0; i < 8; ++i) {
        int row = row0 + wm * 128 + i * 16 + l15;
#pragma unroll
        for (int j = 0; j < 4; ++j) {
            int col = col0 + wn * 64 + j * 16 + l4 * 4;
            *(float4*)&C[(size_t)row * DMODEL + col] =
                make_float4(acc[i][j][0], acc[i][j][1], acc[i][j][2], acc[i][j][3]);
        }
    }
}

// ---------------- launch ----------------

extern "C" void kernel_launch(void* const* d_in, const int* in_sizes, int n_in,
                              void* d_out, int out_size, void* d_ws, size_t ws_size,
                              hipStream_t stream) {
    const float* u      = (const float*)d_in[0];
    const float* logLr  = (const float*)d_in[1];
    const float* Li     = (const float*)d_in[2];
    const float* Br     = (const float*)d_in[3];
    const float* Bi     = (const float*)d_in[4];
    const float* Cr     = (const float*)d_in[5];
    const float* Ci     = (const float*)d_in[6];
    const float* D      = (const float*)d_in[7];
    const float* logDel = (const float*)d_in[8];
    float* out = (float*)d_out;

    const size_t M = (size_t)BATCH * SEQ;  // 32768
    unsigned short* Vb = (unsigned short*)d_ws;       // M*128
    unsigned short* Ub = Vb + M * 128;                // M*512
    unsigned short* Xb = Ub + M * 512;                // M*128
    unsigned short* Mv = Xb + M * 128;                // 128*512
    unsigned short* W  = Mv + 128 * 512;              // 512*640
    float* E     = (float*)(W + 512 * 640);           // 65536

    // fused weight build (Mv + W)
    hipLaunchKernelGGL(k_build, dim3(640), dim3(640), 0, stream,
                       logLr, Li, logDel, Br, Bi, Cr, Ci, D, Mv, W);

    // GEMM1: Vb = bf16(U @ Mv^T), Ub = bf16(U), E = chunk-end states (fused)
    hipLaunchKernelGGL(gemm1, dim3(M / 64), dim3(512), 0, stream,
                       u, Mv, Vb, Ub, logLr, Li, logDel, E);

    // scan: 4-way-ILP carry + serial recurrence -> Xb
    hipLaunchKernelGGL(k_scanCB, dim3(256), dim3(128), 0, stream,
                       Vb, E, logLr, Li, logDel, Xb);

    // GEMM23: out = [Xb | Ub] @ W^T
    hipLaunchKernelGGL(gemm23_8p, dim3(M / 256, DMODEL / 256), dim3(512), 0, stream,
                       Xb, Ub, W, out);
}